// Round 6
// baseline (54.304 us; speedup 1.0000x reference)
//
#include <hip/hip_runtime.h>

#define RADIUS 4
#define KK 81
#define HWP 4096

typedef _Float16 f16x8 __attribute__((ext_vector_type(8)));
typedef _Float16 f16x4 __attribute__((ext_vector_type(4)));
typedef float    f32x4 __attribute__((ext_vector_type(4)));

// ws byte-offset layout (f16 channel-last staging)
#define OFF_F1T  0u
#define OFF_L0   4194304u
#define OFF_L1   8388608u
#define OFF_L2   9437184u
#define OFF_L3   9699328u
#define OFF_ZPAD 9764864u        // 512 B of zeros (filled by stage_kernel block 0)
#define OFF_END  9765376u

// ---------- fused staging: all 5 transposes (f32 [B,256,S] -> f16 [B,S,256]) ----------
__global__ __launch_bounds__(256) void stage_kernel(
    const float* __restrict__ f1, const float* __restrict__ l0,
    const float* __restrict__ l1, const float* __restrict__ l2,
    const float* __restrict__ l3, char* __restrict__ wsB)
{
    __shared__ float tile[32][36];   // pad 36: 16B-aligned rows, 2-way max LDS aliasing
    const int bx = blockIdx.x;    // 0..297
    const int b  = blockIdx.z;
    const int r0 = blockIdx.y * 32;
    const int t  = threadIdx.x;   // 0..255
    if (bx == 0 && blockIdx.y == 0 && b == 0 && t < 128)
        ((float*)(wsB + OFF_ZPAD))[t] = 0.0f;   // zero pad record
    const float* src; _Float16* dst; int S, s0i;
    if (bx < 128)      { src = f1; dst = (_Float16*)(wsB + OFF_F1T); S = 4096; s0i = bx; }
    else if (bx < 256) { src = l0; dst = (_Float16*)(wsB + OFF_L0);  S = 4096; s0i = bx - 128; }
    else if (bx < 288) { src = l1; dst = (_Float16*)(wsB + OFF_L1);  S = 1024; s0i = bx - 256; }
    else if (bx < 296) { src = l2; dst = (_Float16*)(wsB + OFF_L2);  S = 256;  s0i = bx - 288; }
    else               { src = l3; dst = (_Float16*)(wsB + OFF_L3);  S = 64;   s0i = bx - 296; }
    const int s0 = s0i * 32;
    src += (size_t)b * 256 * S;
    dst += (size_t)b * S * 256;
    {
        const int row = t >> 3, cg = t & 7;
        *(f32x4*)&tile[row][cg * 4] =
            *(const f32x4*)&src[(size_t)(r0 + row) * S + s0 + cg * 4];
    }
    __syncthreads();
    {
        const int sidx = t >> 3, chg = t & 7;
        f16x4 o;
        o[0] = (_Float16)tile[chg * 4 + 0][sidx];
        o[1] = (_Float16)tile[chg * 4 + 1][sidx];
        o[2] = (_Float16)tile[chg * 4 + 2][sidx];
        o[3] = (_Float16)tile[chg * 4 + 3][sidx];
        *(f16x4*)&dst[(size_t)(s0 + sidx) * 256 + r0 + chg * 4] = o;
    }
}

// ---------- main: 8x8-px tiles (64 px), 4 A-sets/wave, barrier-free gather-GEMM ----------
// R6 theory: all R0-R5 schedules delivered a CONSTANT ~13 B/cyc/CU gather rate
// (~8 TB/s chip) -> we are bytes-bound, not schedule-bound. Only lever: request
// fewer bytes. 64-px tiles halve the box/tile overlap ratio vs 32-px (~12x vs
// ~29x at lvl0). Each wave holds A-frags for ALL 64 px (4 sets, 128 VGPR) and
// walks disjoint units u = wid (mod 4) with the R4-proven asm ping-pong; each
// 8-KB unit is consumed by 32 MFMA covering the whole tile. No in-loop barriers.
// Block ids pair heavy+light levels (even: lvl0/1, odd: lvl3/2) so the 2
// blocks/CU sum to ~uniform work regardless of dispatcher packing.
__global__ __launch_bounds__(256, 2) void corr_mfma_kernel(
    const char* __restrict__ wsB,
    const float* __restrict__ coords,
    float* __restrict__ out)           // [B,324,4096]
{
    __shared__ float sD[64][104];      // per-px 10x10 window dots
    __shared__ int   sIx[64], sIy[64];
    __shared__ float sW[64][4];
    __shared__ int   sBox[5];          // rlo, cfi, ntw, ntot, inv

    const int id  = blockIdx.x;                   // 0..511
    const int par = id & 1;
    const int kk  = id >> 1;                      // 0..255
    const int lvl = (par == 0) ? ((kk < 128) ? 0 : 1) : ((kk < 128) ? 3 : 2);
    const int tid = kk & 127;                     // 128 tiles per level
    const int b   = tid >> 6;
    const int t6  = tid & 63;                     // 8x8 grid of 8x8-px tiles
    const int tr8 = (t6 >> 3) << 3;
    const int tc8 = (t6 & 7) << 3;
    const int t   = threadIdx.x;                  // 0..255
    const int l   = t & 63;
    const int wid = t >> 6;                       // wave 0..3

    const int sh = 6 - lvl;
    const int W2 = 1 << sh;

    for (int i = t; i < 64 * 104; i += 256)
        ((float*)sD)[i] = 0.0f;

    if (t < 64) {
        const int hwc = ((tr8 + (t >> 3)) << 6) + tc8 + (t & 7);
        const float sc = 1.0f / (float)(1 << lvl);
        const float xs = coords[((size_t)b * 2 + 0) * HWP + hwc] * sc;
        const float ys = coords[((size_t)b * 2 + 1) * HWP + hwc] * sc;
        const float x0f = floorf(xs), y0f = floorf(ys);
        sIx[t] = (int)x0f; sIy[t] = (int)y0f;
        const float fx = xs - x0f, fy = ys - y0f;
        sW[t][0] = (1.f - fx) * (1.f - fy);
        sW[t][1] = fx * (1.f - fy);
        sW[t][2] = (1.f - fx) * fy;
        sW[t][3] = fx * fy;
    }
    __syncthreads();
    if (t == 0) {
        int rlo = 1 << 20, rhi = -(1 << 20), clo = 1 << 20, chi = -(1 << 20);
        for (int px = 0; px < 64; ++px) {
            rlo = min(rlo, sIy[px]); rhi = max(rhi, sIy[px]);
            clo = min(clo, sIx[px]); chi = max(chi, sIx[px]);
        }
        const int rl = max(rlo - RADIUS, 0);
        const int rh = min(rhi + RADIUS + 1, W2 - 1);
        const int cf = max(clo - RADIUS, 0);
        const int ce = min(chi + RADIUS + 1, W2 - 1);
        const int nr = rh - rl + 1;
        const int nt = (ce >= cf) ? ((ce - cf + 16) >> 4) : 0;
        sBox[0] = rl;
        sBox[1] = cf;
        sBox[2] = nt;
        sBox[3] = (nr > 0) ? nr * nt : 0;
        sBox[4] = 65535 / max(nt, 1) + 1;     // exact u/nt = (u*inv)>>16 for u<512,nt<=8
    }

    // A fragments for 4 sets = all 64 px (verified R9 mapping: lane l&15 = px-in-set,
    // l>>4 = k-chunk). Set s covers tile rows 2s, 2s+1.
#define ALOADS(S_) \
    const int hwA##S_ = ((tr8 + 2 * (S_) + ((l & 15) >> 3)) << 6) + tc8 + (l & 7); \
    const char* ap##S_ = wsB + OFF_F1T + ((size_t)(b * HWP + hwA##S_)) * 512 + ((l >> 4) << 4); \
    const f16x8 a##S_##0 = __builtin_bit_cast(f16x8, *(const f32x4*)(ap##S_)); \
    const f16x8 a##S_##1 = __builtin_bit_cast(f16x8, *(const f32x4*)(ap##S_ + 64)); \
    const f16x8 a##S_##2 = __builtin_bit_cast(f16x8, *(const f32x4*)(ap##S_ + 128)); \
    const f16x8 a##S_##3 = __builtin_bit_cast(f16x8, *(const f32x4*)(ap##S_ + 192)); \
    const f16x8 a##S_##4 = __builtin_bit_cast(f16x8, *(const f32x4*)(ap##S_ + 256)); \
    const f16x8 a##S_##5 = __builtin_bit_cast(f16x8, *(const f32x4*)(ap##S_ + 320)); \
    const f16x8 a##S_##6 = __builtin_bit_cast(f16x8, *(const f32x4*)(ap##S_ + 384)); \
    const f16x8 a##S_##7 = __builtin_bit_cast(f16x8, *(const f32x4*)(ap##S_ + 448));
    ALOADS(0) ALOADS(1) ALOADS(2) ALOADS(3)
#undef ALOADS

    // packed scatter coords: lane scatters px (s*16 + pgl + j); pack (4-iy | 4-ix) 16:16
    const int pgl = (l >> 4) << 2;
#define PKD(S_, J_) const int pk##S_##J_ = \
        ((4 - sIy[(S_) * 16 + pgl + (J_)]) << 16) | ((4 - sIx[(S_) * 16 + pgl + (J_)]) & 0xffff);
    PKD(0,0) PKD(0,1) PKD(0,2) PKD(0,3)
    PKD(1,0) PKD(1,1) PKD(1,2) PKD(1,3)
    PKD(2,0) PKD(2,1) PKD(2,2) PKD(2,3)
    PKD(3,0) PKD(3,1) PKD(3,2) PKD(3,3)
#undef PKD
    __syncthreads();                      // publish sBox (drains A-loads too)

    const int rlo = sBox[0], cfi = sBox[1], ntw = sBox[2];
    const int ntot = sBox[3], inv = sBox[4];
    const unsigned lvbase = ((lvl == 0) ? OFF_L0 : (lvl == 1) ? OFF_L1
                           : (lvl == 2) ? OFF_L2 : OFF_L3)
                          + (((unsigned)b << (2 * sh)) << 9);
    const int coff = l & 15;
    const int ksub = (l >> 4) << 4;
    const unsigned zp = OFF_ZPAD + (unsigned)ksub;

    // drain all compiler-tracked VMEM so in-loop vmcnt counts ONLY our asm loads
    asm volatile("s_waitcnt vmcnt(0)" ::: "memory");
    __builtin_amdgcn_sched_barrier(0);

#define DECODE(U_, RR_, JJ_) { const unsigned q__ = ((unsigned)((U_) * inv)) >> 16; \
        JJ_ = (U_) - (int)q__ * ntw; RR_ = rlo + (int)q__; }

#define ISSUE(R_, J_, B0, B1, B2, B3, B4, B5, B6, B7) { \
        const int col_ = cfi + ((J_) << 4) + coff; \
        const bool ok_ = (unsigned)col_ < (unsigned)W2; \
        const unsigned cb_ = ok_ ? (lvbase + ((unsigned)(((R_) << sh) + col_) << 9) + (unsigned)ksub) : zp; \
        const char* gp_ = wsB + cb_; \
        asm volatile("global_load_dwordx4 %0, %1, off"            : "=v"(B0) : "v"(gp_)); \
        asm volatile("global_load_dwordx4 %0, %1, off offset:64"  : "=v"(B1) : "v"(gp_)); \
        asm volatile("global_load_dwordx4 %0, %1, off offset:128" : "=v"(B2) : "v"(gp_)); \
        asm volatile("global_load_dwordx4 %0, %1, off offset:192" : "=v"(B3) : "v"(gp_)); \
        asm volatile("global_load_dwordx4 %0, %1, off offset:256" : "=v"(B4) : "v"(gp_)); \
        asm volatile("global_load_dwordx4 %0, %1, off offset:320" : "=v"(B5) : "v"(gp_)); \
        asm volatile("global_load_dwordx4 %0, %1, off offset:384" : "=v"(B6) : "v"(gp_)); \
        asm volatile("global_load_dwordx4 %0, %1, off offset:448" : "=v"(B7) : "v"(gp_)); }

#define WAITV8 { asm volatile("s_waitcnt vmcnt(8)" ::: "memory"); __builtin_amdgcn_sched_barrier(0); }
#define WAITV0 { asm volatile("s_waitcnt vmcnt(0)" ::: "memory"); __builtin_amdgcn_sched_barrier(0); }

// one A-set vs the unit: 8 MFMA + 4 packed-coord scatters
#define CONSET(S_, B0, B1, B2, B3, B4, B5, B6, B7) { \
        f32x4 ac0 = {0.f,0.f,0.f,0.f}, ac1 = {0.f,0.f,0.f,0.f}; \
        ac0 = __builtin_amdgcn_mfma_f32_16x16x32_f16(a##S_##0, __builtin_bit_cast(f16x8, B0), ac0, 0, 0, 0); \
        ac1 = __builtin_amdgcn_mfma_f32_16x16x32_f16(a##S_##1, __builtin_bit_cast(f16x8, B1), ac1, 0, 0, 0); \
        ac0 = __builtin_amdgcn_mfma_f32_16x16x32_f16(a##S_##2, __builtin_bit_cast(f16x8, B2), ac0, 0, 0, 0); \
        ac1 = __builtin_amdgcn_mfma_f32_16x16x32_f16(a##S_##3, __builtin_bit_cast(f16x8, B3), ac1, 0, 0, 0); \
        ac0 = __builtin_amdgcn_mfma_f32_16x16x32_f16(a##S_##4, __builtin_bit_cast(f16x8, B4), ac0, 0, 0, 0); \
        ac1 = __builtin_amdgcn_mfma_f32_16x16x32_f16(a##S_##5, __builtin_bit_cast(f16x8, B5), ac1, 0, 0, 0); \
        ac0 = __builtin_amdgcn_mfma_f32_16x16x32_f16(a##S_##6, __builtin_bit_cast(f16x8, B6), ac0, 0, 0, 0); \
        ac1 = __builtin_amdgcn_mfma_f32_16x16x32_f16(a##S_##7, __builtin_bit_cast(f16x8, B7), ac1, 0, 0, 0); \
        const f32x4 ss = ac0 + ac1; \
        { const int p = row_ + (pk##S_##0 >> 16), q = col_ + ((pk##S_##0 << 16) >> 16); \
          if ((unsigned)p < 10u && (unsigned)q < 10u) sD[(S_)*16 + pgl + 0][p * 10 + q] = ss[0]; } \
        { const int p = row_ + (pk##S_##1 >> 16), q = col_ + ((pk##S_##1 << 16) >> 16); \
          if ((unsigned)p < 10u && (unsigned)q < 10u) sD[(S_)*16 + pgl + 1][p * 10 + q] = ss[1]; } \
        { const int p = row_ + (pk##S_##2 >> 16), q = col_ + ((pk##S_##2 << 16) >> 16); \
          if ((unsigned)p < 10u && (unsigned)q < 10u) sD[(S_)*16 + pgl + 2][p * 10 + q] = ss[2]; } \
        { const int p = row_ + (pk##S_##3 >> 16), q = col_ + ((pk##S_##3 << 16) >> 16); \
          if ((unsigned)p < 10u && (unsigned)q < 10u) sD[(S_)*16 + pgl + 3][p * 10 + q] = ss[3]; } }

#define CONSUMET(R_, J_, B0, B1, B2, B3, B4, B5, B6, B7) { \
        const int row_ = (R_); \
        const int col_ = cfi + ((J_) << 4) + coff; \
        CONSET(0, B0, B1, B2, B3, B4, B5, B6, B7) \
        CONSET(1, B0, B1, B2, B3, B4, B5, B6, B7) \
        CONSET(2, B0, B1, B2, B3, B4, B5, B6, B7) \
        CONSET(3, B0, B1, B2, B3, B4, B5, B6, B7) }

    // per-wave ping-pong over units u = wid, wid+4, ... (no barriers in loop)
    {
        f32x4 X0, X1, X2, X3, X4, X5, X6, X7;
        f32x4 Y0, Y1, Y2, Y3, Y4, Y5, Y6, Y7;
        int ua = wid;
        if (ua < ntot) {
            int ra, ja, rb, jb;
            DECODE(ua, ra, ja);
            ISSUE(ra, ja, X0, X1, X2, X3, X4, X5, X6, X7);
            int ub = ua + 4;
            for (;;) {
                const bool bv = (ub < ntot);
                if (bv) { DECODE(ub, rb, jb); ISSUE(rb, jb, Y0, Y1, Y2, Y3, Y4, Y5, Y6, Y7); WAITV8; }
                else    { WAITV0; }
                CONSUMET(ra, ja, X0, X1, X2, X3, X4, X5, X6, X7);
                if (!bv) break;
                ua = ub + 4;
                const bool av = (ua < ntot);
                if (av) { DECODE(ua, ra, ja); ISSUE(ra, ja, X0, X1, X2, X3, X4, X5, X6, X7); WAITV8; }
                else    { WAITV0; }
                CONSUMET(rb, jb, Y0, Y1, Y2, Y3, Y4, Y5, Y6, Y7);
                if (!av) break;
                ub = ua + 4;
            }
        }
    }
#undef DECODE
#undef ISSUE
#undef WAITV8
#undef WAITV0
#undef CONSET
#undef CONSUMET
    __syncthreads();

    // bilinear combine + store (this level's 81 channels, 64 pixels)
    for (int j = t; j < 64 * KK; j += 256) {
        const int px = j & 63;
        const int k  = j >> 6;           // 0..80
        const int p  = (k * 57) >> 9;    // k/9
        const int q  = k - p * 9;
        const int bi = p * 10 + q;
        const float* dd = sD[px];
        const float v = (sW[px][0] * dd[bi]      + sW[px][1] * dd[bi + 1] +
                         sW[px][2] * dd[bi + 10] + sW[px][3] * dd[bi + 11]) * 0.0625f;
        const int hwp = ((tr8 + (px >> 3)) << 6) + tc8 + (px & 7);
        out[((size_t)b * 324 + lvl * KK + k) * HWP + hwp] = v;
    }
}

// ---------- fallback (Round-2 verified, original layouts) ----------
__global__ __launch_bounds__(128) void corr_level_kernel(
    const float* __restrict__ f1, const float* __restrict__ f2,
    const float* __restrict__ coords, float* __restrict__ out,
    int H2, int W2, float scale, int lvl)
{
    __shared__ float sf1[256];
    __shared__ float sDl[100];
    const int pix = blockIdx.x;
    const int b   = pix >> 12;
    const int hw  = pix & 4095;
    const int t   = threadIdx.x;
    for (int c = t; c < 256; c += 128)
        sf1[c] = f1[((size_t)b * 256 + c) * 4096 + hw];
    __syncthreads();
    const float xs = coords[((size_t)b * 2 + 0) * 4096 + hw] * scale;
    const float ys = coords[((size_t)b * 2 + 1) * 4096 + hw] * scale;
    const float x0f = floorf(xs), y0f = floorf(ys);
    const float fx = xs - x0f, fy = ys - y0f;
    const int ix0 = (int)x0f, iy0 = (int)y0f;
    if (t < 100) {
        const int p = t / 10, q = t - p * 10;
        const int row = iy0 - 4 + p, col = ix0 - 4 + q;
        float acc = 0.0f;
        if (row >= 0 && row < H2 && col >= 0 && col < W2) {
            const size_t step = (size_t)H2 * W2;
            const size_t base = (size_t)b * 256 * step + (size_t)row * W2 + col;
            #pragma unroll 4
            for (int c = 0; c < 256; ++c)
                acc += f2[base + (size_t)c * step] * sf1[c];
        }
        sDl[t] = acc;
    }
    __syncthreads();
    if (t < 81) {
        const int p = t / 9, q = t - p * 9;
        const float d00 = sDl[p * 10 + q];
        const float d01 = sDl[p * 10 + q + 1];
        const float d10 = sDl[p * 10 + q + 10];
        const float d11 = sDl[p * 10 + q + 11];
        const float v = (1.0f - fy) * ((1.0f - fx) * d00 + fx * d01)
                      + fy * ((1.0f - fx) * d10 + fx * d11);
        out[((size_t)b * 324 + (size_t)lvl * 81 + t) * 4096 + hw] = v * 0.0625f;
    }
}

extern "C" void kernel_launch(void* const* d_in, const int* in_sizes, int n_in,
                              void* d_out, int out_size, void* d_ws, size_t ws_size,
                              hipStream_t stream) {
    (void)out_size;
    const float* f1     = (const float*)d_in[0];
    const float* f2l[4] = {(const float*)d_in[1], (const float*)d_in[2],
                           (const float*)d_in[3], (const float*)d_in[4]};
    const float* coords = (const float*)d_in[5];

    // Size-based identification (input order proved unreliable in R1).
    {
        int nbig = 0;
        for (int i = 0; i < n_in; ++i) {
            const int sz = in_sizes[i];
            if (sz == 2097152) {
                if (nbig == 0) f1 = (const float*)d_in[i];
                else           f2l[0] = (const float*)d_in[i];
                ++nbig;
            }
            else if (sz == 524288) f2l[1] = (const float*)d_in[i];
            else if (sz == 131072) f2l[2] = (const float*)d_in[i];
            else if (sz ==  32768) f2l[3] = (const float*)d_in[i];
            else if (sz ==  16384) coords = (const float*)d_in[i];
        }
    }
    float* out = (float*)d_out;
    char*  wsB = (char*)d_ws;

    if (ws_size >= (size_t)OFF_END) {
        stage_kernel<<<dim3(298, 8, 2), dim3(256, 1, 1), 0, stream>>>(
            f1, f2l[0], f2l[1], f2l[2], f2l[3], wsB);
        corr_mfma_kernel<<<dim3(512, 1, 1), 256, 0, stream>>>(wsB, coords, out);
    } else {
        for (int lvl = 0; lvl < 4; ++lvl) {
            const int W2 = 64 >> lvl;
            const float scale = 1.0f / (float)(1 << lvl);
            corr_level_kernel<<<8192, 128, 0, stream>>>(
                f1, f2l[lvl], coords, out, W2, W2, scale, lvl);
        }
    }
}

// Round 7
// 47.123 us; speedup vs baseline: 1.1524x; 1.1524x over previous
//
#include <hip/hip_runtime.h>

#define RADIUS 4
#define KK 81
#define HWP 4096

typedef _Float16 f16x8 __attribute__((ext_vector_type(8)));
typedef _Float16 f16x4 __attribute__((ext_vector_type(4)));
typedef float    f32x4 __attribute__((ext_vector_type(4)));

// ws byte-offset layout (f16 channel-last staging)
#define OFF_F1T  0u
#define OFF_L0   4194304u
#define OFF_L1   8388608u
#define OFF_L2   9437184u
#define OFF_L3   9699328u
#define OFF_ZPAD 9764864u        // 512 B of zeros (filled by stage_kernel block 0)
#define OFF_END  9765376u

// ---------- fused staging: all 5 transposes (f32 [B,256,S] -> f16 [B,S,256]) ----------
__global__ __launch_bounds__(256) void stage_kernel(
    const float* __restrict__ f1, const float* __restrict__ l0,
    const float* __restrict__ l1, const float* __restrict__ l2,
    const float* __restrict__ l3, char* __restrict__ wsB)
{
    __shared__ float tile[32][36];
    const int bx = blockIdx.x;    // 0..297
    const int b  = blockIdx.z;
    const int r0 = blockIdx.y * 32;
    const int t  = threadIdx.x;   // 0..255
    if (bx == 0 && blockIdx.y == 0 && b == 0 && t < 128)
        ((float*)(wsB + OFF_ZPAD))[t] = 0.0f;   // zero pad record
    const float* src; _Float16* dst; int S, s0i;
    if (bx < 128)      { src = f1; dst = (_Float16*)(wsB + OFF_F1T); S = 4096; s0i = bx; }
    else if (bx < 256) { src = l0; dst = (_Float16*)(wsB + OFF_L0);  S = 4096; s0i = bx - 128; }
    else if (bx < 288) { src = l1; dst = (_Float16*)(wsB + OFF_L1);  S = 1024; s0i = bx - 256; }
    else if (bx < 296) { src = l2; dst = (_Float16*)(wsB + OFF_L2);  S = 256;  s0i = bx - 288; }
    else               { src = l3; dst = (_Float16*)(wsB + OFF_L3);  S = 64;   s0i = bx - 296; }
    const int s0 = s0i * 32;
    src += (size_t)b * 256 * S;
    dst += (size_t)b * S * 256;
    {
        const int row = t >> 3, cg = t & 7;
        *(f32x4*)&tile[row][cg * 4] =
            *(const f32x4*)&src[(size_t)(r0 + row) * S + s0 + cg * 4];
    }
    __syncthreads();
    {
        const int sidx = t >> 3, chg = t & 7;
        f16x4 o;
        o[0] = (_Float16)tile[chg * 4 + 0][sidx];
        o[1] = (_Float16)tile[chg * 4 + 1][sidx];
        o[2] = (_Float16)tile[chg * 4 + 2][sidx];
        o[3] = (_Float16)tile[chg * 4 + 3][sidx];
        *(f16x4*)&dst[(size_t)(s0 + sidx) * 256 + r0 + chg * 4] = o;
    }
}

// in-loop barrier: wait LDS ops only; staging global loads stay in flight
#define BARRIER_LW { asm volatile("s_waitcnt lgkmcnt(0)" ::: "memory"); \
                     __builtin_amdgcn_s_barrier(); \
                     __builtin_amdgcn_sched_barrier(0); }

// ---------- main: 8x8-px tiles, COALESCED LDS staging, 4-wave shared units ----------
// R7 theory: every prior round gathered B with lane=pixel scattered dwordx4 (16
// separate 64-B lines/instr) and all delivered a constant ~12 B/cyc/CU -> TCP
// scattered-line service limit. Now each unit (16 cols x 256 ch = 8 KB) is loaded
// by 256 threads as CONTIGUOUS 1024-B wave-instrs and staged to LDS in an
// XOR-swizzled (g,col) layout; all 4 waves consume it (own 16-px A-set). 64-px
// tiles halve requested bytes (~82 MB). Level->block mapping is XCD-balanced:
// ids 8k..8k+7 = one level spread over all 8 XCDs; co-resident pairs (0,3)/(1,2).
__global__ __launch_bounds__(256, 2) void corr_mfma_kernel(
    const char* __restrict__ wsB,
    const float* __restrict__ coords,
    float* __restrict__ out)           // [B,324,4096]
{
    __shared__ f32x4 sB[2][1024];      // 2 bufs x 16 KB (each: two 8-KB units)
    __shared__ float sD[64][104];      // per-px 10x10 window dots
    __shared__ int   sIx[64], sIy[64];
    __shared__ float sW[64][4];
    __shared__ int   sBox[5];          // rlo, cfi, ntw, ntot, inv

    char* sBb = (char*)sB;

    const int id   = blockIdx.x;                  // 0..511
    const int gq   = id >> 3;                     // 0..63
    const int xcd  = id & 7;
    const int l4   = gq & 3;
    const int lvl  = (gq < 32) ? l4 : 3 - l4;     // balanced across XCDs & pairs
    const int slot = gq >> 2;                     // 0..15
    const int tid  = slot * 8 + xcd;              // 0..127 per level
    const int b    = tid >> 6;
    const int t6   = tid & 63;                    // 8x8 grid of 8x8-px tiles
    const int tr8  = (t6 >> 3) << 3;
    const int tc8  = (t6 & 7) << 3;
    const int t    = threadIdx.x;                 // 0..255
    const int l    = t & 63;
    const int wid  = t >> 6;                      // wave 0..3 = A-set id

    const int sh = 6 - lvl;
    const int W2 = 1 << sh;

    for (int i = t; i < 64 * 104; i += 256)
        ((float*)sD)[i] = 0.0f;

    if (t < 64) {
        const int hwc = ((tr8 + (t >> 3)) << 6) + tc8 + (t & 7);
        const float sc = 1.0f / (float)(1 << lvl);
        const float xs = coords[((size_t)b * 2 + 0) * HWP + hwc] * sc;
        const float ys = coords[((size_t)b * 2 + 1) * HWP + hwc] * sc;
        const float x0f = floorf(xs), y0f = floorf(ys);
        sIx[t] = (int)x0f; sIy[t] = (int)y0f;
        const float fx = xs - x0f, fy = ys - y0f;
        sW[t][0] = (1.f - fx) * (1.f - fy);
        sW[t][1] = fx * (1.f - fy);
        sW[t][2] = (1.f - fx) * fy;
        sW[t][3] = fx * fy;
    }
    __syncthreads();
    if (t == 0) {
        int rlo = 1 << 20, rhi = -(1 << 20), clo = 1 << 20, chi = -(1 << 20);
        for (int px = 0; px < 64; ++px) {
            rlo = min(rlo, sIy[px]); rhi = max(rhi, sIy[px]);
            clo = min(clo, sIx[px]); chi = max(chi, sIx[px]);
        }
        const int rl = max(rlo - RADIUS, 0);
        const int rh = min(rhi + RADIUS + 1, W2 - 1);
        const int cf = max(clo - RADIUS, 0);
        const int ce = min(chi + RADIUS + 1, W2 - 1);
        const int nr = rh - rl + 1;
        const int nt = (ce >= cf) ? ((ce - cf + 16) >> 4) : 0;
        sBox[0] = rl;
        sBox[1] = cf;
        sBox[2] = nt;
        sBox[3] = (nr > 0) ? nr * nt : 0;
        sBox[4] = 65535 / max(nt, 1) + 1;     // exact u/nt = (u*inv)>>16 for u<512,nt<=8
    }

    // A fragments, ONE 16-px set per wave (verified mapping: lane = px (l&15), k-chunk (l>>4))
    const int pxa = (wid << 4) + (l & 15);
    const int hwA = ((tr8 + (pxa >> 3)) << 6) + tc8 + (pxa & 7);
    const char* ap = wsB + OFF_F1T + ((size_t)(b * HWP + hwA)) * 512 + ((l >> 4) << 4);
    const f16x8 a0 = __builtin_bit_cast(f16x8, *(const f32x4*)(ap));
    const f16x8 a1 = __builtin_bit_cast(f16x8, *(const f32x4*)(ap + 64));
    const f16x8 a2 = __builtin_bit_cast(f16x8, *(const f32x4*)(ap + 128));
    const f16x8 a3 = __builtin_bit_cast(f16x8, *(const f32x4*)(ap + 192));
    const f16x8 a4 = __builtin_bit_cast(f16x8, *(const f32x4*)(ap + 256));
    const f16x8 a5 = __builtin_bit_cast(f16x8, *(const f32x4*)(ap + 320));
    const f16x8 a6 = __builtin_bit_cast(f16x8, *(const f32x4*)(ap + 384));
    const f16x8 a7 = __builtin_bit_cast(f16x8, *(const f32x4*)(ap + 448));

    // scatter coords for this lane's 4 pixels of its wave's A-set, packed (4-iy | 4-ix)
    const int pgl = (l >> 4) << 2;
#define PK(J_) const int pk##J_ = ((4 - sIy[(wid << 4) + pgl + (J_)]) << 16) \
                                | ((4 - sIx[(wid << 4) + pgl + (J_)]) & 0xffff);
    PK(0) PK(1) PK(2) PK(3)
#undef PK
    __syncthreads();                      // publish sBox; drain A/coord loads

    const int rlo = sBox[0], cfi = sBox[1], ntw = sBox[2];
    const int ntot = sBox[3], inv = sBox[4];
    const int NP = (ntot + 1) >> 1;       // phases (2 units each)
    const unsigned lvbase = ((lvl == 0) ? OFF_L0 : (lvl == 1) ? OFF_L1
                           : (lvl == 2) ? OFF_L2 : OFF_L3)
                          + (((unsigned)b << (2 * sh)) << 9);
    const int coff = l & 15;

    // staging thread mapping: covers (col = t>>5 [+8], g = t&31); wave-instr = 1024 B contiguous
    const int scol = t >> 5;              // 0..7
    const int sg   = t & 31;              // 0..31
    // swizzled LDS offset within unit: addr(g,col) = g*256 + ((col&8)|((col&7)^(g&7)))*16
    const int wb0  = sg * 256 + ((scol ^ (sg & 7)) << 4);         // col = scol (bit3=0)
    const unsigned zpt = OFF_ZPAD + (unsigned)(sg << 4);
    // consume frag read bases (two, even/odd k-chunk-pairs), same swizzle bijection
    const int xor0  = (l & 7) ^ (l >> 4);
    const int baseE = (l >> 4) * 256 + (((l & 8) | xor0) << 4);
    const int baseO = (l >> 4) * 256 + 1024 + (((l & 8) | (xor0 ^ 4)) << 4);

#define DECODE(U_, RR_, JJ_) { const unsigned q__ = ((unsigned)((U_) * inv)) >> 16; \
        JJ_ = (U_) - (int)q__ * ntw; RR_ = rlo + (int)q__; }

// coalesced load of one unit-half pair for phase P: 4 x 16 B per thread
#define LOADP(P_, R0_, R1_, R2_, R3_) { \
        { const int u_ = (P_) << 1; int r_, j_; DECODE(u_, r_, j_); \
          const int c0_ = cfi + (j_ << 4) + scol; \
          const unsigned rb_ = lvbase + ((unsigned)(r_ << sh) << 9) + (unsigned)(sg << 4); \
          const char* g0_ = wsB + (((unsigned)c0_ < (unsigned)W2 && u_ < ntot) ? (rb_ + ((unsigned)c0_ << 9)) : zpt); \
          const char* g1_ = wsB + (((unsigned)(c0_ + 8) < (unsigned)W2 && u_ < ntot) ? (rb_ + ((unsigned)(c0_ + 8) << 9)) : zpt); \
          R0_ = *(const f32x4*)(g0_); \
          R1_ = *(const f32x4*)(g1_); } \
        { const int u_ = ((P_) << 1) + 1; int r_, j_; DECODE(u_, r_, j_); \
          const int c0_ = cfi + (j_ << 4) + scol; \
          const unsigned rb_ = lvbase + ((unsigned)(r_ << sh) << 9) + (unsigned)(sg << 4); \
          const char* g0_ = wsB + (((unsigned)c0_ < (unsigned)W2 && u_ < ntot) ? (rb_ + ((unsigned)c0_ << 9)) : zpt); \
          const char* g1_ = wsB + (((unsigned)(c0_ + 8) < (unsigned)W2 && u_ < ntot) ? (rb_ + ((unsigned)(c0_ + 8) << 9)) : zpt); \
          R2_ = *(const f32x4*)(g0_); \
          R3_ = *(const f32x4*)(g1_); } \
        __builtin_amdgcn_sched_barrier(0); }

// swizzled LDS publish (compiler inserts counted vmcnt before these ds_writes)
#define WRITEP(BUF_, R0_, R1_, R2_, R3_) { \
        char* wp_ = sBb + ((BUF_) << 14) + wb0; \
        *(f32x4*)(wp_)        = R0_; \
        *(f32x4*)(wp_ + 128)  = R1_; \
        *(f32x4*)(wp_ + 8192) = R2_; \
        *(f32x4*)(wp_ + 8320) = R3_; }

// one unit vs this wave's A-set: 8 swizzled ds_read_b128 + 8 MFMA + 4 scatters
#define CONS1(BASEB_, U_) { \
        int r_, j_; DECODE(U_, r_, j_); \
        const char* pE_ = (BASEB_) + baseE; \
        const char* pO_ = (BASEB_) + baseO; \
        const f16x8 b0_ = __builtin_bit_cast(f16x8, *(const f32x4*)(pE_)); \
        const f16x8 b1_ = __builtin_bit_cast(f16x8, *(const f32x4*)(pO_)); \
        const f16x8 b2_ = __builtin_bit_cast(f16x8, *(const f32x4*)(pE_ + 2048)); \
        const f16x8 b3_ = __builtin_bit_cast(f16x8, *(const f32x4*)(pO_ + 2048)); \
        const f16x8 b4_ = __builtin_bit_cast(f16x8, *(const f32x4*)(pE_ + 4096)); \
        const f16x8 b5_ = __builtin_bit_cast(f16x8, *(const f32x4*)(pO_ + 4096)); \
        const f16x8 b6_ = __builtin_bit_cast(f16x8, *(const f32x4*)(pE_ + 6144)); \
        const f16x8 b7_ = __builtin_bit_cast(f16x8, *(const f32x4*)(pO_ + 6144)); \
        f32x4 ac0 = {0.f, 0.f, 0.f, 0.f}; \
        f32x4 ac1 = {0.f, 0.f, 0.f, 0.f}; \
        ac0 = __builtin_amdgcn_mfma_f32_16x16x32_f16(a0, b0_, ac0, 0, 0, 0); \
        ac1 = __builtin_amdgcn_mfma_f32_16x16x32_f16(a1, b1_, ac1, 0, 0, 0); \
        ac0 = __builtin_amdgcn_mfma_f32_16x16x32_f16(a2, b2_, ac0, 0, 0, 0); \
        ac1 = __builtin_amdgcn_mfma_f32_16x16x32_f16(a3, b3_, ac1, 0, 0, 0); \
        ac0 = __builtin_amdgcn_mfma_f32_16x16x32_f16(a4, b4_, ac0, 0, 0, 0); \
        ac1 = __builtin_amdgcn_mfma_f32_16x16x32_f16(a5, b5_, ac1, 0, 0, 0); \
        ac0 = __builtin_amdgcn_mfma_f32_16x16x32_f16(a6, b6_, ac0, 0, 0, 0); \
        ac1 = __builtin_amdgcn_mfma_f32_16x16x32_f16(a7, b7_, ac1, 0, 0, 0); \
        const f32x4 ss = ac0 + ac1; \
        const int col_ = cfi + (j_ << 4) + coff; \
        { const int p_ = r_ + (pk0 >> 16), q_ = col_ + ((pk0 << 16) >> 16); \
          if ((unsigned)p_ < 10u && (unsigned)q_ < 10u) sD[(wid << 4) + pgl + 0][p_ * 10 + q_] = ss[0]; } \
        { const int p_ = r_ + (pk1 >> 16), q_ = col_ + ((pk1 << 16) >> 16); \
          if ((unsigned)p_ < 10u && (unsigned)q_ < 10u) sD[(wid << 4) + pgl + 1][p_ * 10 + q_] = ss[1]; } \
        { const int p_ = r_ + (pk2 >> 16), q_ = col_ + ((pk2 << 16) >> 16); \
          if ((unsigned)p_ < 10u && (unsigned)q_ < 10u) sD[(wid << 4) + pgl + 2][p_ * 10 + q_] = ss[2]; } \
        { const int p_ = r_ + (pk3 >> 16), q_ = col_ + ((pk3 << 16) >> 16); \
          if ((unsigned)p_ < 10u && (unsigned)q_ < 10u) sD[(wid << 4) + pgl + 3][p_ * 10 + q_] = ss[3]; } }

#define CONSUMEP(BUF_, P_) { \
        const char* bb_ = sBb + ((BUF_) << 14); \
        const int u0_ = (P_) << 1; \
        CONS1(bb_, u0_); \
        if (u0_ + 1 < ntot) { CONS1(bb_ + 8192, u0_ + 1); } }

    {
        f32x4 XA, XB, XC, XD, YA, YB, YC, YD;
        if (ntot > 0) {
            LOADP(0, XA, XB, XC, XD);
            if (NP > 1) LOADP(1, YA, YB, YC, YD);
            WRITEP(0, XA, XB, XC, XD);
        }
        BARRIER_LW;                          // buf0 ready; phase-1 loads in flight
        if (ntot > 0) {
            int p = 0;
            for (;;) {
                if (p + 2 < NP) LOADP(p + 2, XA, XB, XC, XD);
                CONSUMEP(p & 1, p);
                if (p + 1 < NP) WRITEP((p + 1) & 1, YA, YB, YC, YD);
                BARRIER_LW;
                if (++p >= NP) break;
                if (p + 2 < NP) LOADP(p + 2, YA, YB, YC, YD);
                CONSUMEP(p & 1, p);
                if (p + 1 < NP) WRITEP((p + 1) & 1, XA, XB, XC, XD);
                BARRIER_LW;
                if (++p >= NP) break;
            }
        }
    }
#undef DECODE
#undef LOADP
#undef WRITEP
#undef CONS1
#undef CONSUMEP
    __syncthreads();

    // bilinear combine + store (this level's 81 channels, 64 pixels)
    for (int j = t; j < 64 * KK; j += 256) {
        const int px = j & 63;
        const int k  = j >> 6;           // 0..80
        const int p  = (k * 57) >> 9;    // k/9
        const int q  = k - p * 9;
        const int bi = p * 10 + q;
        const float* dd = sD[px];
        const float v = (sW[px][0] * dd[bi]      + sW[px][1] * dd[bi + 1] +
                         sW[px][2] * dd[bi + 10] + sW[px][3] * dd[bi + 11]) * 0.0625f;
        const int hwp = ((tr8 + (px >> 3)) << 6) + tc8 + (px & 7);
        out[((size_t)b * 324 + lvl * KK + k) * HWP + hwp] = v;
    }
}

// ---------- fallback (Round-2 verified, original layouts) ----------
__global__ __launch_bounds__(128) void corr_level_kernel(
    const float* __restrict__ f1, const float* __restrict__ f2,
    const float* __restrict__ coords, float* __restrict__ out,
    int H2, int W2, float scale, int lvl)
{
    __shared__ float sf1[256];
    __shared__ float sDl[100];
    const int pix = blockIdx.x;
    const int b   = pix >> 12;
    const int hw  = pix & 4095;
    const int t   = threadIdx.x;
    for (int c = t; c < 256; c += 128)
        sf1[c] = f1[((size_t)b * 256 + c) * 4096 + hw];
    __syncthreads();
    const float xs = coords[((size_t)b * 2 + 0) * 4096 + hw] * scale;
    const float ys = coords[((size_t)b * 2 + 1) * 4096 + hw] * scale;
    const float x0f = floorf(xs), y0f = floorf(ys);
    const float fx = xs - x0f, fy = ys - y0f;
    const int ix0 = (int)x0f, iy0 = (int)y0f;
    if (t < 100) {
        const int p = t / 10, q = t - p * 10;
        const int row = iy0 - 4 + p, col = ix0 - 4 + q;
        float acc = 0.0f;
        if (row >= 0 && row < H2 && col >= 0 && col < W2) {
            const size_t step = (size_t)H2 * W2;
            const size_t base = (size_t)b * 256 * step + (size_t)row * W2 + col;
            #pragma unroll 4
            for (int c = 0; c < 256; ++c)
                acc += f2[base + (size_t)c * step] * sf1[c];
        }
        sDl[t] = acc;
    }
    __syncthreads();
    if (t < 81) {
        const int p = t / 9, q = t - p * 9;
        const float d00 = sDl[p * 10 + q];
        const float d01 = sDl[p * 10 + q + 1];
        const float d10 = sDl[p * 10 + q + 10];
        const float d11 = sDl[p * 10 + q + 11];
        const float v = (1.0f - fy) * ((1.0f - fx) * d00 + fx * d01)
                      + fy * ((1.0f - fx) * d10 + fx * d11);
        out[((size_t)b * 324 + (size_t)lvl * 81 + t) * 4096 + hw] = v * 0.0625f;
    }
}

extern "C" void kernel_launch(void* const* d_in, const int* in_sizes, int n_in,
                              void* d_out, int out_size, void* d_ws, size_t ws_size,
                              hipStream_t stream) {
    (void)out_size;
    const float* f1     = (const float*)d_in[0];
    const float* f2l[4] = {(const float*)d_in[1], (const float*)d_in[2],
                           (const float*)d_in[3], (const float*)d_in[4]};
    const float* coords = (const float*)d_in[5];

    // Size-based identification (input order proved unreliable in R1).
    {
        int nbig = 0;
        for (int i = 0; i < n_in; ++i) {
            const int sz = in_sizes[i];
            if (sz == 2097152) {
                if (nbig == 0) f1 = (const float*)d_in[i];
                else           f2l[0] = (const float*)d_in[i];
                ++nbig;
            }
            else if (sz == 524288) f2l[1] = (const float*)d_in[i];
            else if (sz == 131072) f2l[2] = (const float*)d_in[i];
            else if (sz ==  32768) f2l[3] = (const float*)d_in[i];
            else if (sz ==  16384) coords = (const float*)d_in[i];
        }
    }
    float* out = (float*)d_out;
    char*  wsB = (char*)d_ws;

    if (ws_size >= (size_t)OFF_END) {
        stage_kernel<<<dim3(298, 8, 2), dim3(256, 1, 1), 0, stream>>>(
            f1, f2l[0], f2l[1], f2l[2], f2l[3], wsB);
        corr_mfma_kernel<<<dim3(512, 1, 1), 256, 0, stream>>>(wsB, coords, out);
    } else {
        for (int lvl = 0; lvl < 4; ++lvl) {
            const int W2 = 64 >> lvl;
            const float scale = 1.0f / (float)(1 << lvl);
            corr_level_kernel<<<8192, 128, 0, stream>>>(
                f1, f2l[lvl], coords, out, W2, W2, scale, lvl);
        }
    }
}

// Round 8
// 43.957 us; speedup vs baseline: 1.2354x; 1.0720x over previous
//
#include <hip/hip_runtime.h>

#define RADIUS 4
#define KK 81
#define HWP 4096

typedef _Float16 f16x8 __attribute__((ext_vector_type(8)));
typedef float    f32x4 __attribute__((ext_vector_type(4)));

// ws byte-offset layout (f16 channel-last staging)
#define OFF_F1T  0u
#define OFF_L0   4194304u
#define OFF_L1   8388608u
#define OFF_L2   9437184u
#define OFF_L3   9699328u
#define OFF_ZPAD 9764864u        // 512 B of zeros (filled by stage_kernel block 0)
#define OFF_END  9765376u

// ---------- fused staging: all 5 transposes (f32 [B,256,S] -> f16 [B,S,256]) ----------
__global__ __launch_bounds__(256) void stage_kernel(
    const float* __restrict__ f1, const float* __restrict__ l0,
    const float* __restrict__ l1, const float* __restrict__ l2,
    const float* __restrict__ l3, char* __restrict__ wsB)
{
    __shared__ float tile[32][33];
    const int bx = blockIdx.x;    // 0..297
    const int b  = blockIdx.z;
    const int r0 = blockIdx.y * 32;
    const int tx = threadIdx.x, ty = threadIdx.y;   // 32 x 8
    if (bx == 0 && blockIdx.y == 0 && b == 0) {
        const int tt = ty * 32 + tx;
        if (tt < 128) ((float*)(wsB + OFF_ZPAD))[tt] = 0.0f;   // zero pad record
    }
    const float* src; _Float16* dst; int S, s0i;
    if (bx < 128)      { src = f1; dst = (_Float16*)(wsB + OFF_F1T); S = 4096; s0i = bx; }
    else if (bx < 256) { src = l0; dst = (_Float16*)(wsB + OFF_L0);  S = 4096; s0i = bx - 128; }
    else if (bx < 288) { src = l1; dst = (_Float16*)(wsB + OFF_L1);  S = 1024; s0i = bx - 256; }
    else if (bx < 296) { src = l2; dst = (_Float16*)(wsB + OFF_L2);  S = 256;  s0i = bx - 288; }
    else               { src = l3; dst = (_Float16*)(wsB + OFF_L3);  S = 64;   s0i = bx - 296; }
    const int s0 = s0i * 32;
    src += (size_t)b * 256 * S;
    dst += (size_t)b * S * 256;
    #pragma unroll
    for (int i = 0; i < 32; i += 8)
        tile[ty + i][tx] = src[(size_t)(r0 + ty + i) * S + s0 + tx];
    __syncthreads();
    #pragma unroll
    for (int i = 0; i < 32; i += 8)
        dst[(size_t)(s0 + ty + i) * 256 + r0 + tx] = (_Float16)tile[tx][ty + i];
}

// ---------- main: 8x4-pixel tiles (32 px), paired-unit LDS pipeline ----------
// EXACT R2 structure (best measured: 44.53 us) with two measured-defect fixes:
//  * sD stride 104 -> 106 floats (stride%8==2 => the four 16-lane scatter groups
//    land on banks {0-15,8-23,16-31,24-7}: uniform 2 lanes/bank = free, vs the
//    4-way conflicts behind SQ_LDS_BANK_CONFLICT=1.1-2.4M in R0/R6)
//  * s_setprio(1) around the MFMA cluster (T5; phases here have wave role split)
__global__ __launch_bounds__(256, 3) void corr_mfma_kernel(
    const char* __restrict__ wsB,
    const float* __restrict__ coords,
    float* __restrict__ out)           // [B,324,4096]
{
    __shared__ f32x4 sB[2][1024];      // 2 x 16KB (two 8-KB unit-halves each)
    __shared__ float sD[32][106];      // per-px 10x10 window dots (padded stride)
    __shared__ int   sIx[32], sIy[32];
    __shared__ float sW[32][4];
    __shared__ int   sBox[5];          // rlo, cfi, ntw, ntot, inv

    char* sBb = (char*)sB;

    const int bx   = blockIdx.x;                  // 0..255
    const int lvl  = blockIdx.y;                  // 0..3
    const int tile = ((bx & 7) << 5) | (bx >> 3); // XCD swizzle (bijective on 256)
    const int b    = tile >> 7;
    const int t7   = tile & 127;                  // 128 tiles per batch: 16 rows x 8 cols
    const int tr4  = (t7 >> 3) << 2;              // tile pixel-row base (4 tall)
    const int tc8  = (t7 & 7) << 3;               // tile pixel-col base (8 wide)
    const int t    = threadIdx.x;                 // 0..255
    const int l    = t & 63;
    const int wid  = t >> 6;                      // wave 0..3
    const int aset = wid & 1;                     // which 16-px A tile
    const int half = wid >> 1;                    // which unit of the pair

    const int sh = 6 - lvl;
    const int W2 = 1 << sh;

    for (int i = t; i < 32 * 106; i += 256)
        ((float*)sD)[i] = 0.0f;

    if (t < 32) {
        const int hwc = ((tr4 + (t >> 3)) << 6) + tc8 + (t & 7);
        const float sc = 1.0f / (float)(1 << lvl);
        const float xs = coords[((size_t)b * 2 + 0) * HWP + hwc] * sc;
        const float ys = coords[((size_t)b * 2 + 1) * HWP + hwc] * sc;
        const float x0f = floorf(xs), y0f = floorf(ys);
        sIx[t] = (int)x0f; sIy[t] = (int)y0f;
        const float fx = xs - x0f, fy = ys - y0f;
        sW[t][0] = (1.f - fx) * (1.f - fy);
        sW[t][1] = fx * (1.f - fy);
        sW[t][2] = (1.f - fx) * fy;
        sW[t][3] = fx * fy;
    }
    __syncthreads();
    if (t == 0) {
        int rlo = 1 << 20, rhi = -(1 << 20), clo = 1 << 20, chi = -(1 << 20);
        for (int px = 0; px < 32; ++px) {
            rlo = min(rlo, sIy[px]); rhi = max(rhi, sIy[px]);
            clo = min(clo, sIx[px]); chi = max(chi, sIx[px]);
        }
        const int rl = max(rlo - RADIUS, 0);
        const int rh = min(rhi + RADIUS + 1, W2 - 1);
        const int cf = max(clo - RADIUS, 0);
        const int ce = min(chi + RADIUS + 1, W2 - 1);
        const int nr = rh - rl + 1;
        const int nt = (ce >= cf) ? ((ce - cf + 16) >> 4) : 0;
        sBox[0] = rl;
        sBox[1] = cf;
        sBox[2] = nt;
        sBox[3] = (nr > 0) ? nr * nt : 0;
        sBox[4] = 65535 / max(nt, 1) + 1;     // exact u/nt = (u*inv)>>16 for u<512,nt<=8
    }

    // A fragments (verified R9 mapping): lane l = local px (l&15) in A-set, k-chunk (l>>4)
    const int pxl = (aset << 4) + (l & 15);
    const int hwA = ((tr4 + (pxl >> 3)) << 6) + tc8 + (pxl & 7);
    const char* ap = wsB + OFF_F1T + ((size_t)(b * HWP + hwA)) * 512 + ((l >> 4) << 4);
    const f16x8 a0 = __builtin_bit_cast(f16x8, *(const f32x4*)(ap));
    const f16x8 a1 = __builtin_bit_cast(f16x8, *(const f32x4*)(ap + 64));
    const f16x8 a2 = __builtin_bit_cast(f16x8, *(const f32x4*)(ap + 128));
    const f16x8 a3 = __builtin_bit_cast(f16x8, *(const f32x4*)(ap + 192));
    const f16x8 a4 = __builtin_bit_cast(f16x8, *(const f32x4*)(ap + 256));
    const f16x8 a5 = __builtin_bit_cast(f16x8, *(const f32x4*)(ap + 320));
    const f16x8 a6 = __builtin_bit_cast(f16x8, *(const f32x4*)(ap + 384));
    const f16x8 a7 = __builtin_bit_cast(f16x8, *(const f32x4*)(ap + 448));
    __syncthreads();                      // publish sBox

    const int rlo = sBox[0], cfi = sBox[1], ntw = sBox[2];
    const int ntot = sBox[3], inv = sBox[4];
    const int NP = (ntot + 1) >> 1;       // phases (2 units each)
    const unsigned lvbase = ((lvl == 0) ? OFF_L0 : (lvl == 1) ? OFF_L1
                           : (lvl == 2) ? OFF_L2 : OFF_L3)
                          + (((unsigned)b << (2 * sh)) << 9);
    const int coff = l & 15;

    const int pxg  = (aset << 4) + ((l >> 4) << 2);  // this lane's 4 scatter pixels
    const int iy0r = sIy[pxg + 0], ix0r = sIx[pxg + 0];
    const int iy1r = sIy[pxg + 1], ix1r = sIx[pxg + 1];
    const int iy2r = sIy[pxg + 2], ix2r = sIx[pxg + 2];
    const int iy3r = sIy[pxg + 3], ix3r = sIx[pxg + 3];

// stage loads for phase P: thread t serves unit u=2P+(t>>7), px (t&15), 64B at chunk-group (t>>4)&7
#define LOADP(P_, R0_, R1_, R2_, R3_) { \
        const int u_ = ((P_) << 1) + (t >> 7); \
        const unsigned q_ = ((unsigned)(u_ * inv)) >> 16; \
        const int j_ = u_ - (int)q_ * ntw; \
        const int col_ = cfi + (j_ << 4) + (t & 15); \
        const bool ok_ = (u_ < ntot) && ((unsigned)col_ < (unsigned)W2); \
        const int row_ = rlo + (int)q_; \
        const char* gp_ = wsB + (ok_ ? (lvbase + ((unsigned)((row_ << sh) + col_) << 9)) \
                                     : OFF_ZPAD) + ((unsigned)((t >> 4) & 7) << 6); \
        R0_ = *(const f32x4*)(gp_); \
        R1_ = *(const f32x4*)(gp_ + 16); \
        R2_ = *(const f32x4*)(gp_ + 32); \
        R3_ = *(const f32x4*)(gp_ + 48); \
        __builtin_amdgcn_sched_barrier(0); }

// LDS layout per 8-KB half: byte = g*256 + px*16 (granule g = 16B of channels), proven R1 map
#define WRITEP(BUF_, R0_, R1_, R2_, R3_) { \
        char* wp_ = sBb + ((BUF_) << 14) + ((t >> 7) << 13) + (((t >> 4) & 7) << 10) \
                  + ((t & 15) << 4); \
        *(f32x4*)(wp_)       = R0_; \
        *(f32x4*)(wp_ + 256) = R1_; \
        *(f32x4*)(wp_ + 512) = R2_; \
        *(f32x4*)(wp_ + 768) = R3_; }

// consume this wave's unit of phase P: 8 ds_read_b128 + 8 MFMA + scatter to sD
#define CONSUMEP(BUF_, P_) { \
        const int u_ = ((P_) << 1) + half; \
        if (u_ < ntot) { \
            const unsigned q_ = ((unsigned)(u_ * inv)) >> 16; \
            const int j_ = u_ - (int)q_ * ntw; \
            const int row_ = rlo + (int)q_; \
            const char* lb_ = sBb + ((BUF_) << 14) + (half << 13) + ((l >> 4) << 8) \
                            + ((l & 15) << 4); \
            const f16x8 b0_ = __builtin_bit_cast(f16x8, *(const f32x4*)(lb_)); \
            const f16x8 b1_ = __builtin_bit_cast(f16x8, *(const f32x4*)(lb_ + 1024)); \
            const f16x8 b2_ = __builtin_bit_cast(f16x8, *(const f32x4*)(lb_ + 2048)); \
            const f16x8 b3_ = __builtin_bit_cast(f16x8, *(const f32x4*)(lb_ + 3072)); \
            const f16x8 b4_ = __builtin_bit_cast(f16x8, *(const f32x4*)(lb_ + 4096)); \
            const f16x8 b5_ = __builtin_bit_cast(f16x8, *(const f32x4*)(lb_ + 5120)); \
            const f16x8 b6_ = __builtin_bit_cast(f16x8, *(const f32x4*)(lb_ + 6144)); \
            const f16x8 b7_ = __builtin_bit_cast(f16x8, *(const f32x4*)(lb_ + 7168)); \
            f32x4 ac0 = {0.f, 0.f, 0.f, 0.f}; \
            f32x4 ac1 = {0.f, 0.f, 0.f, 0.f}; \
            __builtin_amdgcn_s_setprio(1); \
            ac0 = __builtin_amdgcn_mfma_f32_16x16x32_f16(a0, b0_, ac0, 0, 0, 0); \
            ac1 = __builtin_amdgcn_mfma_f32_16x16x32_f16(a1, b1_, ac1, 0, 0, 0); \
            ac0 = __builtin_amdgcn_mfma_f32_16x16x32_f16(a2, b2_, ac0, 0, 0, 0); \
            ac1 = __builtin_amdgcn_mfma_f32_16x16x32_f16(a3, b3_, ac1, 0, 0, 0); \
            ac0 = __builtin_amdgcn_mfma_f32_16x16x32_f16(a4, b4_, ac0, 0, 0, 0); \
            ac1 = __builtin_amdgcn_mfma_f32_16x16x32_f16(a5, b5_, ac1, 0, 0, 0); \
            ac0 = __builtin_amdgcn_mfma_f32_16x16x32_f16(a6, b6_, ac0, 0, 0, 0); \
            ac1 = __builtin_amdgcn_mfma_f32_16x16x32_f16(a7, b7_, ac1, 0, 0, 0); \
            __builtin_amdgcn_s_setprio(0); \
            const f32x4 accs = ac0 + ac1; \
            const int col_ = cfi + (j_ << 4) + coff; \
            const int p0 = row_ - iy0r + RADIUS, q0 = col_ - ix0r + RADIUS; \
            if ((unsigned)p0 < 10u && (unsigned)q0 < 10u) sD[pxg + 0][p0 * 10 + q0] = accs[0]; \
            const int p1 = row_ - iy1r + RADIUS, q1 = col_ - ix1r + RADIUS; \
            if ((unsigned)p1 < 10u && (unsigned)q1 < 10u) sD[pxg + 1][p1 * 10 + q1] = accs[1]; \
            const int p2 = row_ - iy2r + RADIUS, q2 = col_ - ix2r + RADIUS; \
            if ((unsigned)p2 < 10u && (unsigned)q2 < 10u) sD[pxg + 2][p2 * 10 + q2] = accs[2]; \
            const int p3 = row_ - iy3r + RADIUS, q3 = col_ - ix3r + RADIUS; \
            if ((unsigned)p3 < 10u && (unsigned)q3 < 10u) sD[pxg + 3][p3 * 10 + q3] = accs[3]; \
        } }

    {
        f32x4 XA, XB, XC, XD, YA, YB, YC, YD;
        if (ntot > 0) {
            LOADP(0, XA, XB, XC, XD);
            if (NP > 1) LOADP(1, YA, YB, YC, YD);
            WRITEP(0, XA, XB, XC, XD);
        }
        __syncthreads();                         // buf0 ready
        if (ntot > 0) {
            int p = 0;
            for (;;) {
                // body A: X free -> prefetch p+2; consume p; publish p+1 (Y)
                if (p + 2 < NP) LOADP(p + 2, XA, XB, XC, XD);
                CONSUMEP(p & 1, p);
                if (p + 1 < NP) WRITEP((p + 1) & 1, YA, YB, YC, YD);
                __syncthreads();
                if (++p >= NP) break;
                // body B: roles swapped (static reg names, rule #20)
                if (p + 2 < NP) LOADP(p + 2, YA, YB, YC, YD);
                CONSUMEP(p & 1, p);
                if (p + 1 < NP) WRITEP((p + 1) & 1, XA, XB, XC, XD);
                __syncthreads();
                if (++p >= NP) break;
            }
        }
    }
#undef LOADP
#undef WRITEP
#undef CONSUMEP
    __syncthreads();

    // bilinear combine + store (this level's 81 channels, 32 pixels)
    for (int j = t; j < 32 * KK; j += 256) {
        const int px = j & 31;
        const int k  = j >> 5;           // 0..80
        const int p  = (k * 57) >> 9;    // k/9
        const int q  = k - p * 9;
        const int bi = p * 10 + q;
        const float* dd = sD[px];
        const float v = (sW[px][0] * dd[bi]      + sW[px][1] * dd[bi + 1] +
                         sW[px][2] * dd[bi + 10] + sW[px][3] * dd[bi + 11]) * 0.0625f;
        const int hwp = ((tr4 + (px >> 3)) << 6) + tc8 + (px & 7);
        out[((size_t)b * 324 + lvl * KK + k) * HWP + hwp] = v;
    }
}

// ---------- fallback (Round-2 verified, original layouts) ----------
__global__ __launch_bounds__(128) void corr_level_kernel(
    const float* __restrict__ f1, const float* __restrict__ f2,
    const float* __restrict__ coords, float* __restrict__ out,
    int H2, int W2, float scale, int lvl)
{
    __shared__ float sf1[256];
    __shared__ float sDl[100];
    const int pix = blockIdx.x;
    const int b   = pix >> 12;
    const int hw  = pix & 4095;
    const int t   = threadIdx.x;
    for (int c = t; c < 256; c += 128)
        sf1[c] = f1[((size_t)b * 256 + c) * 4096 + hw];
    __syncthreads();
    const float xs = coords[((size_t)b * 2 + 0) * 4096 + hw] * scale;
    const float ys = coords[((size_t)b * 2 + 1) * 4096 + hw] * scale;
    const float x0f = floorf(xs), y0f = floorf(ys);
    const float fx = xs - x0f, fy = ys - y0f;
    const int ix0 = (int)x0f, iy0 = (int)y0f;
    if (t < 100) {
        const int p = t / 10, q = t - p * 10;
        const int row = iy0 - 4 + p, col = ix0 - 4 + q;
        float acc = 0.0f;
        if (row >= 0 && row < H2 && col >= 0 && col < W2) {
            const size_t step = (size_t)H2 * W2;
            const size_t base = (size_t)b * 256 * step + (size_t)row * W2 + col;
            #pragma unroll 4
            for (int c = 0; c < 256; ++c)
                acc += f2[base + (size_t)c * step] * sf1[c];
        }
        sDl[t] = acc;
    }
    __syncthreads();
    if (t < 81) {
        const int p = t / 9, q = t - p * 9;
        const float d00 = sDl[p * 10 + q];
        const float d01 = sDl[p * 10 + q + 1];
        const float d10 = sDl[p * 10 + q + 10];
        const float d11 = sDl[p * 10 + q + 11];
        const float v = (1.0f - fy) * ((1.0f - fx) * d00 + fx * d01)
                      + fy * ((1.0f - fx) * d10 + fx * d11);
        out[((size_t)b * 324 + (size_t)lvl * 81 + t) * 4096 + hw] = v * 0.0625f;
    }
}

extern "C" void kernel_launch(void* const* d_in, const int* in_sizes, int n_in,
                              void* d_out, int out_size, void* d_ws, size_t ws_size,
                              hipStream_t stream) {
    (void)out_size;
    const float* f1     = (const float*)d_in[0];
    const float* f2l[4] = {(const float*)d_in[1], (const float*)d_in[2],
                           (const float*)d_in[3], (const float*)d_in[4]};
    const float* coords = (const float*)d_in[5];

    // Size-based identification (input order proved unreliable in R1).
    {
        int nbig = 0;
        for (int i = 0; i < n_in; ++i) {
            const int sz = in_sizes[i];
            if (sz == 2097152) {
                if (nbig == 0) f1 = (const float*)d_in[i];
                else           f2l[0] = (const float*)d_in[i];
                ++nbig;
            }
            else if (sz == 524288) f2l[1] = (const float*)d_in[i];
            else if (sz == 131072) f2l[2] = (const float*)d_in[i];
            else if (sz ==  32768) f2l[3] = (const float*)d_in[i];
            else if (sz ==  16384) coords = (const float*)d_in[i];
        }
    }
    float* out = (float*)d_out;
    char*  wsB = (char*)d_ws;

    if (ws_size >= (size_t)OFF_END) {
        stage_kernel<<<dim3(298, 8, 2), dim3(32, 8, 1), 0, stream>>>(
            f1, f2l[0], f2l[1], f2l[2], f2l[3], wsB);
        corr_mfma_kernel<<<dim3(256, 4, 1), 256, 0, stream>>>(wsB, coords, out);
    } else {
        for (int lvl = 0; lvl < 4; ++lvl) {
            const int W2 = 64 >> lvl;
            const float scale = 1.0f / (float)(1 << lvl);
            corr_level_kernel<<<8192, 128, 0, stream>>>(
                f1, f2l[lvl], coords, out, W2, W2, scale, lvl);
        }
    }
}